// Round 9
// baseline (3579.183 us; speedup 1.0000x reference)
//
#include <hip/hip_runtime.h>
#include <math.h>

#define N_RES 2048
#define N_IN  128
#define T_SEQ 2048
#define NB    128      // blocks in recurrence kernel
#define ROWS  16       // rows per block
#define SENT  0x7F7F7F7Fu   // sentinel (3.39e38); bit30 set. |x|<=0.0222 -> bit30 clear

// ---------------- Kernel 1: U = input @ W_in^T  -> d_out (row t = U[t]) ----
__global__ __launch_bounds__(256) void u_gemm(
    const float* __restrict__ in, const float* __restrict__ win,
    float* __restrict__ out)
{
  __shared__ float As[64][65];
  __shared__ float Bs[64][65];
  const int tid = threadIdx.x;
  const int t0 = blockIdx.y * 64;
  const int n0 = blockIdx.x * 64;
  const int tx = tid & 15, ty = tid >> 4;

  float acc[4][4];
  #pragma unroll
  for (int r = 0; r < 4; ++r)
    #pragma unroll
    for (int c = 0; c < 4; ++c) acc[r][c] = 0.f;

  for (int k0 = 0; k0 < N_IN; k0 += 64) {
    __syncthreads();
    #pragma unroll
    for (int i = 0; i < 4; ++i) {
      int idx = tid + i * 256;
      int row = idx >> 4;
      int k4  = (idx & 15) << 2;
      float4 a = *(const float4*)(in  + (size_t)(t0 + row) * N_IN + k0 + k4);
      As[row][k4+0] = a.x; As[row][k4+1] = a.y; As[row][k4+2] = a.z; As[row][k4+3] = a.w;
      float4 b = *(const float4*)(win + (size_t)(n0 + row) * N_IN + k0 + k4);
      Bs[row][k4+0] = b.x; Bs[row][k4+1] = b.y; Bs[row][k4+2] = b.z; Bs[row][k4+3] = b.w;
    }
    __syncthreads();
    for (int k = 0; k < 64; ++k) {
      float a[4], b[4];
      #pragma unroll
      for (int r = 0; r < 4; ++r) a[r] = As[ty*4+r][k];
      #pragma unroll
      for (int c = 0; c < 4; ++c) b[c] = Bs[tx*4+c][k];
      #pragma unroll
      for (int r = 0; r < 4; ++r)
        #pragma unroll
        for (int c = 0; c < 4; ++c) acc[r][c] += a[r] * b[c];
    }
  }
  #pragma unroll
  for (int r = 0; r < 4; ++r) {
    float4 v = make_float4(acc[r][0], acc[r][1], acc[r][2], acc[r][3]);
    *(float4*)(out + (size_t)(t0 + ty*4 + r) * N_RES + n0 + tx*4) = v;
  }
}

// ---- DPP helpers ----------------------------------------------------------
template<int CTRL>
__device__ __forceinline__ float xdpp(float v)
{
  return __uint_as_float(__builtin_amdgcn_update_dpp(
      0, (int)__float_as_uint(v), CTRL, 0xF, 0xF, true));
}
// quad_perm[1,0,3,2] (xor1) = 0xB1 ; quad_perm[2,3,0,1] (xor2) = 0x4E
// row_ror:8 = 0x128 : within 16-lane rows, (i+8)%16 == i^8 (direction-safe)

// ---- fold-and-keep wave reduction: 16 partials -> 1 full row sum per lane.
// Lane L ends with the complete sum of row rml(L) =
// (L&1)*8 + ((L>>1)&1)*4 + ((L>>2)&1)*2 + ((L>>3)&1)  (bijection on 0..15
// for lanes 0..15, duplicated x4 across the wave).
__device__ __forceinline__ float fold_reduce16(float v[16], int lane)
{
  #pragma unroll
  for (int r = 0; r < 8; ++r) {
    float send = (lane & 1) ? v[r] : v[r + 8];
    float recv = xdpp<0xB1>(send);
    v[r] = ((lane & 1) ? v[r + 8] : v[r]) + recv;
  }
  #pragma unroll
  for (int r = 0; r < 4; ++r) {
    float send = (lane & 2) ? v[r] : v[r + 4];
    float recv = xdpp<0x4E>(send);
    v[r] = ((lane & 2) ? v[r + 4] : v[r]) + recv;
  }
  #pragma unroll
  for (int r = 0; r < 2; ++r) {
    float send = (lane & 4) ? v[r] : v[r + 2];
    float recv = __shfl_xor(send, 4, 64);
    v[r] = ((lane & 4) ? v[r + 2] : v[r]) + recv;
  }
  {
    float send = (lane & 8) ? v[0] : v[1];
    float recv = xdpp<0x128>(send);          // xor8 within 16-lane row
    v[0] = ((lane & 8) ? v[1] : v[0]) + recv;
  }
  v[0] += __shfl_xor(v[0], 16, 64);
  v[0] += __shfl_xor(v[0], 32, 64);
  return v[0];
}

// ---------------- Kernel 2: recurrence, v8 ---------------------------------
// R7 structure + (1) double-buffered poll (two rounds in flight -> detect
// granularity ~halves), (2) up to R=8 xbuf replicas, (3) wave0 keeps its
// partial in-register (waves 1-3 write LDS; one barrier/step, parity-buffered).
__global__ __launch_bounds__(256, 1) void esn_recur_v8(
    const float* __restrict__ wres, float* __restrict__ out,
    unsigned int* __restrict__ xbuf, int R)
{
  const int tid = threadIdx.x;
  const int lane = tid & 63;
  const int row0 = blockIdx.x * ROWS;
  const int wave = tid >> 6;
  const float inv = 0.022097086912079608f;   // 1/sqrt(2048)
  const int rml = (lane & 1) * 8 + ((lane >> 1) & 1) * 4
                + ((lane >> 2) & 1) * 2 + ((lane >> 3) & 1);
  const int rb = blockIdx.x & (R - 1);       // my replica

  // W: w[r][j] = W[row0+r][tid + 256*j]; coalesced, register-resident.
  float w[ROWS][8];
  #pragma unroll
  for (int r = 0; r < ROWS; ++r) {
    const float* p = wres + (size_t)(row0 + r) * N_RES + tid;
    #pragma unroll
    for (int j = 0; j < 8; ++j) w[r][j] = p[j * 256];
  }

  __shared__ float red[2][4][ROWS];   // [t&1][wave][row], waves 1..3 only

  // t = 0: x0 = erf(U[0]) * inv; store to all replicas
  if (tid < ROWS) {
    float x0 = erff(out[row0 + tid]) * inv;
    for (int rep = 0; rep < R; ++rep)
      __hip_atomic_store(xbuf + (size_t)rep * N_RES + row0 + tid,
                         __float_as_uint(x0),
                         __ATOMIC_RELAXED, __HIP_MEMORY_SCOPE_AGENT);
    out[row0 + tid] = x0;
  }
  __syncthreads();

  for (int t = 1; t < T_SEQ; ++t) {
    const int p = t & 1;
    // own U[t] slot for row rml — issued before the poll, hides under it
    float u = out[(size_t)t * N_RES + row0 + rml];

    // ---- double-buffered poll of own 8 x words (bit-30 sentinel test) ----
    const unsigned int* xr = xbuf + ((size_t)(t - 1) * R + rb) * N_RES + tid;
    unsigned int xv[8];
    {
      unsigned int A[8], B[8];
      #pragma unroll
      for (int j = 0; j < 8; ++j)
        A[j] = __hip_atomic_load(xr + j * 256, __ATOMIC_RELAXED,
                                 __HIP_MEMORY_SCOPE_AGENT);
      for (;;) {
        #pragma unroll
        for (int j = 0; j < 8; ++j)
          B[j] = __hip_atomic_load(xr + j * 256, __ATOMIC_RELAXED,
                                   __HIP_MEMORY_SCOPE_AGENT);
        unsigned int orv = (A[0]|A[1]) | (A[2]|A[3]) | (A[4]|A[5]) | (A[6]|A[7]);
        if (!(orv & 0x40000000u)) {
          #pragma unroll
          for (int j = 0; j < 8; ++j) xv[j] = A[j];
          break;
        }
        #pragma unroll
        for (int j = 0; j < 8; ++j)
          A[j] = __hip_atomic_load(xr + j * 256, __ATOMIC_RELAXED,
                                   __HIP_MEMORY_SCOPE_AGENT);
        orv = (B[0]|B[1]) | (B[2]|B[3]) | (B[4]|B[5]) | (B[6]|B[7]);
        if (!(orv & 0x40000000u)) {
          #pragma unroll
          for (int j = 0; j < 8; ++j) xv[j] = B[j];
          break;
        }
      }
    }

    // partial matvec: 16 rows x 8 cols
    float acc[ROWS];
    #pragma unroll
    for (int r = 0; r < ROWS; ++r) {
      acc[r] = w[r][0]*__uint_as_float(xv[0]) + w[r][1]*__uint_as_float(xv[1])
             + w[r][2]*__uint_as_float(xv[2]) + w[r][3]*__uint_as_float(xv[3])
             + w[r][4]*__uint_as_float(xv[4]) + w[r][5]*__uint_as_float(xv[5])
             + w[r][6]*__uint_as_float(xv[6]) + w[r][7]*__uint_as_float(xv[7]);
    }
    float s = fold_reduce16(acc, lane);   // lane holds full sum of row rml

    if (wave != 0 && lane < ROWS) red[p][wave][rml] = s;
    __syncthreads();

    // wave 0, lanes 0..15 finalize row rml (bijection; consistent with u)
    if (tid < ROWS) {
      float tot = s + red[p][1][rml] + red[p][2][rml] + red[p][3][rml];
      float xt = erff(u + tot) * inv;
      unsigned int xu = __float_as_uint(xt);
      unsigned int* dst = xbuf + (size_t)t * R * N_RES + row0 + rml;
      for (int rep = 0; rep < R; ++rep)
        __hip_atomic_store(dst + (size_t)rep * N_RES, xu,
                           __ATOMIC_RELAXED, __HIP_MEMORY_SCOPE_AGENT);
      out[(size_t)t * N_RES + row0 + rml] = xt;   // plain; after signals
    }
    // parity buffer + barrier ordering bounds skew <= 1 step: no 2nd barrier
  }
}

// ---------------- fallback (R2 flag barrier) if ws < 16 MiB ----------------
#define FSTR 4
__global__ __launch_bounds__(256, 1) void esn_recur_flags(
    const float* __restrict__ wres, float* out, int* ws)
{
  const int b = blockIdx.x;
  const int tid = threadIdx.x;
  const int lane = tid & 63;
  const int wave = tid >> 6;
  const int row0 = b * ROWS;
  const float inv = 0.022097086912079608f;

  float w[ROWS][8];
  #pragma unroll
  for (int r = 0; r < ROWS; ++r) {
    const float* p = wres + (size_t)(row0 + r) * N_RES + tid;
    #pragma unroll
    for (int j = 0; j < 8; ++j) w[r][j] = p[j * 256];
  }

  __shared__ float red[ROWS][4];
  int* flags = ws;

  if (tid < ROWS) {
    float u = out[row0 + tid];
    __hip_atomic_store(out + row0 + tid, erff(u) * inv,
                       __ATOMIC_RELAXED, __HIP_MEMORY_SCOPE_AGENT);
  }
  if (wave == 0) {
    asm volatile("s_waitcnt vmcnt(0)" ::: "memory");
    if (lane == 0)
      __hip_atomic_store(flags + b * FSTR, 1, __ATOMIC_RELAXED, __HIP_MEMORY_SCOPE_AGENT);
  }

  for (int t = 1; t < T_SEQ; ++t) {
    if (wave == 0) {
      const int* f0 = flags + lane * FSTR;
      const int* f1 = flags + (lane + 64) * FSTR;
      bool ok;
      do {
        int a = __hip_atomic_load(f0, __ATOMIC_RELAXED, __HIP_MEMORY_SCOPE_AGENT);
        int c = __hip_atomic_load(f1, __ATOMIC_RELAXED, __HIP_MEMORY_SCOPE_AGENT);
        ok = (a >= t) && (c >= t);
      } while (!__all(ok));
    }
    __syncthreads();

    float u = 0.f;
    if (tid < ROWS) u = out[(size_t)t * N_RES + row0 + tid];

    const float* xrow = out + (size_t)(t - 1) * N_RES + tid;
    float x[8];
    #pragma unroll
    for (int j = 0; j < 8; ++j)
      x[j] = __hip_atomic_load(xrow + j * 256, __ATOMIC_RELAXED, __HIP_MEMORY_SCOPE_AGENT);

    float acc[ROWS];
    #pragma unroll
    for (int r = 0; r < ROWS; ++r) {
      acc[r] = w[r][0]*x[0] + w[r][1]*x[1] + w[r][2]*x[2] + w[r][3]*x[3]
             + w[r][4]*x[4] + w[r][5]*x[5] + w[r][6]*x[6] + w[r][7]*x[7];
    }
    #pragma unroll
    for (int m = 1; m < 64; m <<= 1) {
      #pragma unroll
      for (int r = 0; r < ROWS; ++r)
        acc[r] += __shfl_xor(acc[r], m, 64);
    }
    if (lane == 0) {
      #pragma unroll
      for (int r = 0; r < ROWS; ++r) red[r][wave] = acc[r];
    }
    __syncthreads();
    if (tid < ROWS) {
      float s = red[tid][0] + red[tid][1] + red[tid][2] + red[tid][3];
      __hip_atomic_store(out + (size_t)t * N_RES + row0 + tid, erff(u + s) * inv,
                         __ATOMIC_RELAXED, __HIP_MEMORY_SCOPE_AGENT);
    }
    if (wave == 0) {
      asm volatile("s_waitcnt vmcnt(0)" ::: "memory");
      if (lane == 0)
        __hip_atomic_store(flags + b * FSTR, t + 1,
                           __ATOMIC_RELAXED, __HIP_MEMORY_SCOPE_AGENT);
    }
  }
}

extern "C" void kernel_launch(void* const* d_in, const int* in_sizes, int n_in,
                              void* d_out, int out_size, void* d_ws, size_t ws_size,
                              hipStream_t stream)
{
  const float* input = (const float*)d_in[0];
  const float* w_in  = (const float*)d_in[1];
  const float* w_res = (const float*)d_in[2];
  float* out = (float*)d_out;

  const size_t xbytes = (size_t)T_SEQ * N_RES * sizeof(float);  // 16 MiB

  dim3 g1(N_RES / 64, T_SEQ / 64), b1(256);
  hipLaunchKernelGGL(u_gemm, g1, b1, 0, stream, input, w_in, out);

  if (ws_size >= xbytes) {
    int R = 1;                                   // replicas (power of 2, <=8)
    while (R < 8 && (size_t)(2 * R) * xbytes <= ws_size) R *= 2;
    unsigned int* xbuf = (unsigned int*)d_ws;
    hipMemsetAsync(d_ws, 0x7F, (size_t)R * xbytes, stream);  // sentinel-fill
    void* args[] = { (void*)&w_res, (void*)&out, (void*)&xbuf, (void*)&R };
    hipLaunchCooperativeKernel((void*)esn_recur_v8, dim3(NB), dim3(256),
                               args, 0, stream);
  } else {
    int* ws = (int*)d_ws;
    size_t clr = ws_size < 4096 ? ws_size : 4096;
    hipMemsetAsync(d_ws, 0, clr, stream);
    void* args[] = { (void*)&w_res, (void*)&out, (void*)&ws };
    hipLaunchCooperativeKernel((void*)esn_recur_flags, dim3(NB), dim3(256),
                               args, 0, stream);
  }
}